// Round 10
// baseline (53.977 us; speedup 1.0000x reference)
//
#include <hip/hip_runtime.h>
#include <math.h>

#define IMG_H 512
#define IMG_W 512

typedef float f32x4 __attribute__((ext_vector_type(4)));

__device__ __forceinline__ int reflect101(int i, int n) {
    if (i < 0) i = -i;
    if (i >= n) i = 2 * n - 2 - i;
    return i;
}

// 4 aligned float4 loads covering cols b0..b3(+3) of src row RY (row-reflected).
#define LOADROW(RY, A, B, C, D) do {                                          \
    const float* rp_ = ip + (size_t)reflect101((RY), IMG_H) * IMG_W;          \
    A = *(const f32x4*)(rp_ + b0);                                            \
    B = *(const f32x4*)(rp_ + b1);                                            \
    C = *(const f32x4*)(rp_ + b2);                                            \
    D = *(const f32x4*)(rp_ + b3);                                            \
} while (0)

// Quantize 12 used cols (xo-2..xo+9) to integer-valued floats.
// floor(clip(v*255,0,255)) == floorf(v*255) for v in [0,1) (clip inactive).
// Edge column reflect is branchless: clamped bases put the reflected source
// element in the same loaded f4 (le: col -1 -> elem y of A; re: col 512 -> elem z of D).
#define QROW(A, B, C, D, Q) do {                                              \
    float m1_ = le ? A.y : A.w;                                               \
    float c8_ = re ? D.z : D.x;                                               \
    Q##0  = floorf(A.z * 255.0f);                                             \
    Q##1  = floorf(m1_ * 255.0f);                                             \
    Q##2  = floorf(B.x * 255.0f);                                             \
    Q##3  = floorf(B.y * 255.0f);                                             \
    Q##4  = floorf(B.z * 255.0f);                                             \
    Q##5  = floorf(B.w * 255.0f);                                             \
    Q##6  = floorf(C.x * 255.0f);                                             \
    Q##7  = floorf(C.y * 255.0f);                                             \
    Q##8  = floorf(C.z * 255.0f);                                             \
    Q##9  = floorf(C.w * 255.0f);                                             \
    Q##10 = floorf(c8_ * 255.0f);                                             \
    Q##11 = floorf(D.y * 255.0f);                                             \
} while (0)

// Vertical pair-sum row: E = QA + QB  (e(r) = q(r)+q(r+1))
#define EMAKE(E, QA, QB) do {                                                 \
    E##0 = QA##0 + QB##0;   E##1 = QA##1 + QB##1;                             \
    E##2 = QA##2 + QB##2;   E##3 = QA##3 + QB##3;                             \
    E##4 = QA##4 + QB##4;   E##5 = QA##5 + QB##5;                             \
    E##6 = QA##6 + QB##6;   E##7 = QA##7 + QB##7;                             \
    E##8 = QA##8 + QB##8;   E##9 = QA##9 + QB##9;                             \
    E##10 = QA##10 + QB##10; E##11 = QA##11 + QB##11;                         \
} while (0)

// Blur row BL0..BL9 (cols xo-1..xo+8) from cs = EA+EB via shared pair sums d.
// Sums <= 4080 exact; *0.0625 exact; rintf == round-half-even == jnp.round.
#define BLMAKE(BL, EA, EB) do {                                               \
    float cs0 = EA##0 + EB##0,   cs1 = EA##1 + EB##1;                         \
    float cs2 = EA##2 + EB##2,   cs3 = EA##3 + EB##3;                         \
    float cs4 = EA##4 + EB##4,   cs5 = EA##5 + EB##5;                         \
    float cs6 = EA##6 + EB##6,   cs7 = EA##7 + EB##7;                         \
    float cs8 = EA##8 + EB##8,   cs9 = EA##9 + EB##9;                         \
    float cs10 = EA##10 + EB##10, cs11 = EA##11 + EB##11;                     \
    float d0 = cs0 + cs1, d1 = cs1 + cs2, d2 = cs2 + cs3, d3 = cs3 + cs4;     \
    float d4 = cs4 + cs5, d5 = cs5 + cs6, d6 = cs6 + cs7, d7 = cs7 + cs8;     \
    float d8 = cs8 + cs9, d9 = cs9 + cs10, d10 = cs10 + cs11;                 \
    BL##0 = rintf((d0 + d1) * 0.0625f);                                       \
    BL##1 = rintf((d1 + d2) * 0.0625f);                                       \
    BL##2 = rintf((d2 + d3) * 0.0625f);                                       \
    BL##3 = rintf((d3 + d4) * 0.0625f);                                       \
    BL##4 = rintf((d4 + d5) * 0.0625f);                                       \
    BL##5 = rintf((d5 + d6) * 0.0625f);                                       \
    BL##6 = rintf((d6 + d7) * 0.0625f);                                       \
    BL##7 = rintf((d7 + d8) * 0.0625f);                                       \
    BL##8 = rintf((d8 + d9) * 0.0625f);                                       \
    BL##9 = rintf((d9 + d10) * 0.0625f);                                      \
} while (0)

// Laplacian row T: u = BA+BC shared; out col xo+c = min(2*|u[c]+u[c+2]-4*BB[c+1]|,255)
#define OUTROW(BA, BB, BC, T) do {                                            \
    float u0 = BA##0 + BC##0, u1 = BA##1 + BC##1, u2 = BA##2 + BC##2;         \
    float u3 = BA##3 + BC##3, u4 = BA##4 + BC##4, u5 = BA##5 + BC##5;         \
    float u6 = BA##6 + BC##6, u7 = BA##7 + BC##7, u8 = BA##8 + BC##8;         \
    float u9 = BA##9 + BC##9;                                                 \
    f32x4 oA_, oB_;                                                           \
    float h_;                                                                 \
    h_ = fmaf(-4.0f, BB##1, u0 + u2); oA_.x = fminf(2.0f * fabsf(h_), 255.0f);\
    h_ = fmaf(-4.0f, BB##2, u1 + u3); oA_.y = fminf(2.0f * fabsf(h_), 255.0f);\
    h_ = fmaf(-4.0f, BB##3, u2 + u4); oA_.z = fminf(2.0f * fabsf(h_), 255.0f);\
    h_ = fmaf(-4.0f, BB##4, u3 + u5); oA_.w = fminf(2.0f * fabsf(h_), 255.0f);\
    h_ = fmaf(-4.0f, BB##5, u4 + u6); oB_.x = fminf(2.0f * fabsf(h_), 255.0f);\
    h_ = fmaf(-4.0f, BB##6, u5 + u7); oB_.y = fminf(2.0f * fabsf(h_), 255.0f);\
    h_ = fmaf(-4.0f, BB##7, u6 + u8); oB_.z = fminf(2.0f * fabsf(h_), 255.0f);\
    h_ = fmaf(-4.0f, BB##8, u7 + u9); oB_.w = fminf(2.0f * fabsf(h_), 255.0f);\
    float* orow_ = &op[(size_t)(yb + (T)) * IMG_W + xo];                      \
    *(f32x4*)orow_ = oA_;                                                     \
    *(f32x4*)(orow_ + 4) = oB_;                                               \
} while (0)

__global__ __launch_bounds__(256, 4) void lap_fused(const float* __restrict__ in,
                                                    float* __restrict__ out) {
    const int img = blockIdx.z;
    const float* __restrict__ ip = in + (size_t)img * (IMG_H * IMG_W);
    float* __restrict__ op = out + (size_t)img * (IMG_H * IMG_W);
    const int tid = threadIdx.x;

    // 8-wide x 4-tall strip per thread; no LDS, no barriers.
    const int cg = tid & 31;                 // col group
    const int rb = tid >> 5;                 // row band 0..7
    const int xo = blockIdx.x * 256 + 8 * cg;     // out cols xo..xo+7
    const int yb = blockIdx.y * 32 + 4 * rb;      // out rows yb..yb+3

    // clamped aligned f4 bases covering used cols xo-2..xo+9
    const int b0 = (xo == 0) ? 0 : (xo - 4);
    const int b1 = xo;
    const int b2 = xo + 4;
    const int b3 = (xo + 8 > IMG_W - 4) ? (IMG_W - 4) : (xo + 8);
    const bool le = (xo == 0);
    const bool re = (xo + 8 > IMG_W - 4);

    f32x4 A0, B0, C0, D0, A1, B1, C1, D1;    // two row-loads in flight
    float qA0, qA1, qA2, qA3, qA4, qA5, qA6, qA7, qA8, qA9, qA10, qA11;
    float qB0, qB1, qB2, qB3, qB4, qB5, qB6, qB7, qB8, qB9, qB10, qB11;
    float qC0, qC1, qC2, qC3, qC4, qC5, qC6, qC7, qC8, qC9, qC10, qC11;
    float eA0, eA1, eA2, eA3, eA4, eA5, eA6, eA7, eA8, eA9, eA10, eA11;
    float eB0, eB1, eB2, eB3, eB4, eB5, eB6, eB7, eB8, eB9, eB10, eB11;
    float bP0, bP1, bP2, bP3, bP4, bP5, bP6, bP7, bP8, bP9;
    float bQ0, bQ1, bQ2, bQ3, bQ4, bQ5, bQ6, bQ7, bQ8, bQ9;
    float bR0, bR1, bR2, bR3, bR4, bR5, bR6, bR7, bR8, bR9;

    // src rows yb-2 .. yb+5; loads issued 2 rows ahead of consumption
    LOADROW(yb - 2, A0, B0, C0, D0);
    LOADROW(yb - 1, A1, B1, C1, D1);
    QROW(A0, B0, C0, D0, qA);  LOADROW(yb + 0, A0, B0, C0, D0);
    QROW(A1, B1, C1, D1, qB);  LOADROW(yb + 1, A1, B1, C1, D1);
    EMAKE(eA, qA, qB);                                        // e(yb-2)
    QROW(A0, B0, C0, D0, qC);  LOADROW(yb + 2, A0, B0, C0, D0);
    EMAKE(eB, qB, qC);  BLMAKE(bP, eA, eB);                   // bl(yb-1)
    QROW(A1, B1, C1, D1, qA);  LOADROW(yb + 3, A1, B1, C1, D1);
    EMAKE(eA, qC, qA);  BLMAKE(bQ, eB, eA);                   // bl(yb)
    QROW(A0, B0, C0, D0, qB);  LOADROW(yb + 4, A0, B0, C0, D0);
    EMAKE(eB, qA, qB);  BLMAKE(bR, eA, eB);                   // bl(yb+1)
    OUTROW(bP, bQ, bR, 0);
    QROW(A1, B1, C1, D1, qC);  LOADROW(yb + 5, A1, B1, C1, D1);
    EMAKE(eA, qB, qC);  BLMAKE(bP, eB, eA);                   // bl(yb+2)
    OUTROW(bQ, bR, bP, 1);
    QROW(A0, B0, C0, D0, qA);
    EMAKE(eB, qC, qA);  BLMAKE(bQ, eA, eB);                   // bl(yb+3)
    OUTROW(bR, bP, bQ, 2);
    QROW(A1, B1, C1, D1, qB);
    EMAKE(eA, qA, qB);  BLMAKE(bR, eB, eA);                   // bl(yb+4)
    OUTROW(bP, bQ, bR, 3);
}

extern "C" void kernel_launch(void* const* d_in, const int* in_sizes, int n_in,
                              void* d_out, int out_size, void* d_ws, size_t ws_size,
                              hipStream_t stream) {
    const float* x = (const float*)d_in[0];
    float* out = (float*)d_out;
    dim3 grid(IMG_W / 256, IMG_H / 32, 96);  // 2 x 16 x 96 = 3072 blocks
    dim3 block(256);
    lap_fused<<<grid, block, 0, stream>>>(x, out);
}

// Round 11
// 42.789 us; speedup vs baseline: 1.2615x; 1.2615x over previous
//
#include <hip/hip_runtime.h>
#include <math.h>

#define IMG_H 512
#define IMG_W 512
#define TW 256
#define TH 32            // per sub-tile; block marches 4 sub-tiles = 256 x 128
#define SRC_ROWS 36      // TH + 4 (src halo 2 each side)
#define SRC_SLOTS 66     // (TW+8)/4 uint slots; cols gx = tx0-4 .. tx0+259

typedef float f32x4 __attribute__((ext_vector_type(4)));

__device__ __forceinline__ int reflect101(int i, int n) {
    if (i < 0) i = -i;
    if (i >= n) i = 2 * n - 2 - i;
    return i;
}

// floor(clip(v*255,0,255)) for v in [0,1): v_cvt_u32_f32 truncates (=floor) and
// saturates negatives to 0; high clip inactive for uniform[0,1) input.
__device__ __forceinline__ unsigned int quant4(float4 v) {
    unsigned int a = (unsigned int)(v.x * 255.0f);
    unsigned int b = (unsigned int)(v.y * 255.0f);
    unsigned int c = (unsigned int)(v.z * 255.0f);
    unsigned int d = (unsigned int)(v.w * 255.0f);
    return a | (b << 8) | (c << 16) | (d << 24);
}

// ---- Stage-1 pipeline pieces -------------------------------------------------
// Issue all global loads for sub-tile at row base TYB into registers VV/EE.
#define ISSUE_TILE(TYB, VV, EE) do {                                          \
    _Pragma("unroll")                                                         \
    for (int k_ = 0; k_ < 9; ++k_) {                                          \
        int gy_ = reflect101((TYB) + r0s + 4 * k_ - 2, IMG_H);                \
        VV[k_] = *(const float4*)(ip + (size_t)gy_ * IMG_W + gxs);            \
    }                                                                         \
    if (tid < 72) {                                                           \
        int gy_ = reflect101((TYB) + (tid >> 1) - 2, IMG_H);                  \
        const float* rowp_ = ip + (size_t)gy_ * IMG_W;                        \
        float* pe_ = (float*)&EE;                                             \
        _Pragma("unroll")                                                     \
        for (int k2_ = 0; k2_ < 4; ++k2_)                                     \
            pe_[k2_] = rowp_[reflect101(gxe + k2_, IMG_W)];                   \
    }                                                                         \
} while (0)

// Quantize+pack registers into LDS buffer S.
#define PACK_TILE(S, VV, EE) do {                                             \
    _Pragma("unroll")                                                         \
    for (int k_ = 0; k_ < 9; ++k_) s_src[S][r0s + 4 * k_][js] = quant4(VV[k_]);\
    if (tid < 72) s_src[S][tid >> 1][je] = quant4(EE);                        \
} while (0)

// ---- Compute pieces ----------------------------------------------------------
#define LOADR(S, k, RA, RB) do {                                              \
    RA = *(const uint2*)&s_src[S][lr0 + (k)][sb];                             \
    RB = *(const uint2*)&s_src[S][lr0 + (k)][sb + 2];                         \
} while (0)

#define UNPK(RA, RB, Q) do {                                                  \
    Q##0  = (float)((RA.x >> 16) & 0xffu);                                    \
    Q##1  = (float)(RA.x >> 24);                                              \
    Q##2  = (float)(RA.y & 0xffu);                                            \
    Q##3  = (float)((RA.y >> 8) & 0xffu);                                     \
    Q##4  = (float)((RA.y >> 16) & 0xffu);                                    \
    Q##5  = (float)(RA.y >> 24);                                              \
    Q##6  = (float)(RB.x & 0xffu);                                            \
    Q##7  = (float)((RB.x >> 8) & 0xffu);                                     \
    Q##8  = (float)((RB.x >> 16) & 0xffu);                                    \
    Q##9  = (float)(RB.x >> 24);                                              \
    Q##10 = (float)(RB.y & 0xffu);                                            \
    Q##11 = (float)((RB.y >> 8) & 0xffu);                                     \
} while (0)

#define EMAKE(E, QA, QB) do {                                                 \
    E##0 = QA##0 + QB##0;   E##1 = QA##1 + QB##1;                             \
    E##2 = QA##2 + QB##2;   E##3 = QA##3 + QB##3;                             \
    E##4 = QA##4 + QB##4;   E##5 = QA##5 + QB##5;                             \
    E##6 = QA##6 + QB##6;   E##7 = QA##7 + QB##7;                             \
    E##8 = QA##8 + QB##8;   E##9 = QA##9 + QB##9;                             \
    E##10 = QA##10 + QB##10; E##11 = QA##11 + QB##11;                         \
} while (0)

// Sums <= 4080 exact; *0.0625 exact; rintf == round-half-even == jnp.round.
#define BLMAKE(BL, EA, EB) do {                                               \
    float cs0 = EA##0 + EB##0,   cs1 = EA##1 + EB##1;                         \
    float cs2 = EA##2 + EB##2,   cs3 = EA##3 + EB##3;                         \
    float cs4 = EA##4 + EB##4,   cs5 = EA##5 + EB##5;                         \
    float cs6 = EA##6 + EB##6,   cs7 = EA##7 + EB##7;                         \
    float cs8 = EA##8 + EB##8,   cs9 = EA##9 + EB##9;                         \
    float cs10 = EA##10 + EB##10, cs11 = EA##11 + EB##11;                     \
    float d0 = cs0 + cs1, d1 = cs1 + cs2, d2 = cs2 + cs3, d3 = cs3 + cs4;     \
    float d4 = cs4 + cs5, d5 = cs5 + cs6, d6 = cs6 + cs7, d7 = cs7 + cs8;     \
    float d8 = cs8 + cs9, d9 = cs9 + cs10, d10 = cs10 + cs11;                 \
    BL##0 = rintf((d0 + d1) * 0.0625f);                                       \
    BL##1 = rintf((d1 + d2) * 0.0625f);                                       \
    BL##2 = rintf((d2 + d3) * 0.0625f);                                       \
    BL##3 = rintf((d3 + d4) * 0.0625f);                                       \
    BL##4 = rintf((d4 + d5) * 0.0625f);                                       \
    BL##5 = rintf((d5 + d6) * 0.0625f);                                       \
    BL##6 = rintf((d6 + d7) * 0.0625f);                                       \
    BL##7 = rintf((d7 + d8) * 0.0625f);                                       \
    BL##8 = rintf((d8 + d9) * 0.0625f);                                       \
    BL##9 = rintf((d9 + d10) * 0.0625f);                                      \
} while (0)

#define OUTROW(BA, BB, BC, T, OB) do {                                        \
    float u0 = BA##0 + BC##0, u1 = BA##1 + BC##1, u2 = BA##2 + BC##2;         \
    float u3 = BA##3 + BC##3, u4 = BA##4 + BC##4, u5 = BA##5 + BC##5;         \
    float u6 = BA##6 + BC##6, u7 = BA##7 + BC##7, u8 = BA##8 + BC##8;         \
    float u9 = BA##9 + BC##9;                                                 \
    f32x4 oA_, oB_;                                                           \
    float h_;                                                                 \
    h_ = fmaf(-4.0f, BB##1, u0 + u2); oA_.x = fminf(2.0f * fabsf(h_), 255.0f);\
    h_ = fmaf(-4.0f, BB##2, u1 + u3); oA_.y = fminf(2.0f * fabsf(h_), 255.0f);\
    h_ = fmaf(-4.0f, BB##3, u2 + u4); oA_.z = fminf(2.0f * fabsf(h_), 255.0f);\
    h_ = fmaf(-4.0f, BB##4, u3 + u5); oA_.w = fminf(2.0f * fabsf(h_), 255.0f);\
    h_ = fmaf(-4.0f, BB##5, u4 + u6); oB_.x = fminf(2.0f * fabsf(h_), 255.0f);\
    h_ = fmaf(-4.0f, BB##6, u5 + u7); oB_.y = fminf(2.0f * fabsf(h_), 255.0f);\
    h_ = fmaf(-4.0f, BB##7, u6 + u8); oB_.z = fminf(2.0f * fabsf(h_), 255.0f);\
    h_ = fmaf(-4.0f, BB##8, u7 + u9); oB_.w = fminf(2.0f * fabsf(h_), 255.0f);\
    float* orow_ = &op[(size_t)((OB) + yb + (T)) * IMG_W + xo];               \
    *(f32x4*)orow_ = oA_;                                                     \
    *(f32x4*)(orow_ + 4) = oB_;                                               \
} while (0)

// Full sub-tile compute: 8 wide x 4 tall per thread, straight-line, rolling rows.
#define COMPUTE_TILE(S, OB) do {                                              \
    uint2 r0a, r0b, r1a, r1b, r2a, r2b, r3a, r3b;                             \
    uint2 r4a, r4b, r5a, r5b, r6a, r6b, r7a, r7b;                             \
    float qA0, qA1, qA2, qA3, qA4, qA5, qA6, qA7, qA8, qA9, qA10, qA11;       \
    float qB0, qB1, qB2, qB3, qB4, qB5, qB6, qB7, qB8, qB9, qB10, qB11;       \
    float eA0, eA1, eA2, eA3, eA4, eA5, eA6, eA7, eA8, eA9, eA10, eA11;       \
    float eB0, eB1, eB2, eB3, eB4, eB5, eB6, eB7, eB8, eB9, eB10, eB11;       \
    float bP0, bP1, bP2, bP3, bP4, bP5, bP6, bP7, bP8, bP9;                   \
    float bQ0, bQ1, bQ2, bQ3, bQ4, bQ5, bQ6, bQ7, bQ8, bQ9;                   \
    float bR0, bR1, bR2, bR3, bR4, bR5, bR6, bR7, bR8, bR9;                   \
    LOADR(S, 0, r0a, r0b); LOADR(S, 1, r1a, r1b);                             \
    LOADR(S, 2, r2a, r2b); LOADR(S, 3, r3a, r3b);                             \
    UNPK(r0a, r0b, qA);                                                       \
    UNPK(r1a, r1b, qB);  EMAKE(eA, qA, qB);                                   \
    LOADR(S, 4, r4a, r4b);                                                    \
    UNPK(r2a, r2b, qA);  EMAKE(eB, qB, qA);  BLMAKE(bP, eA, eB);              \
    LOADR(S, 5, r5a, r5b);                                                    \
    UNPK(r3a, r3b, qB);  EMAKE(eA, qA, qB);  BLMAKE(bQ, eB, eA);              \
    LOADR(S, 6, r6a, r6b);                                                    \
    UNPK(r4a, r4b, qA);  EMAKE(eB, qB, qA);  BLMAKE(bR, eA, eB);              \
    OUTROW(bP, bQ, bR, 0, OB);                                                \
    LOADR(S, 7, r7a, r7b);                                                    \
    UNPK(r5a, r5b, qB);  EMAKE(eA, qA, qB);  BLMAKE(bP, eB, eA);              \
    OUTROW(bQ, bR, bP, 1, OB);                                                \
    UNPK(r6a, r6b, qA);  EMAKE(eB, qB, qA);  BLMAKE(bQ, eA, eB);              \
    OUTROW(bR, bP, bQ, 2, OB);                                                \
    UNPK(r7a, r7b, qB);  EMAKE(eA, qA, qB);  BLMAKE(bR, eB, eA);              \
    OUTROW(bP, bQ, bR, 3, OB);                                                \
} while (0)

__global__ __launch_bounds__(256, 4) void lap_fused(const float* __restrict__ in,
                                                    float* __restrict__ out) {
    __shared__ unsigned int s_src[2][SRC_ROWS][SRC_SLOTS];  // 19008 B double-buffer

    const int img = blockIdx.z;
    const int ty0 = blockIdx.y * (4 * TH);   // block marches rows ty0 .. ty0+127
    const int tx0 = blockIdx.x * TW;
    const float* __restrict__ ip = in + (size_t)img * (IMG_H * IMG_W);
    float* __restrict__ op = out + (size_t)img * (IMG_H * IMG_W);
    const int tid = threadIdx.x;

    // stage-1 thread mapping (interior slots j=1..64 aligned float4; edges j=0,65)
    const int js = 1 + (tid & 63);
    const int r0s = tid >> 6;                // 0..3
    const int gxs = tx0 - 4 + 4 * js;        // in [0,508] for all tiles
    const int je = (tid & 1) * 65;
    const int gxe = tx0 - 4 + 4 * je;

    // compute thread mapping (8 wide x 4 tall strips)
    const int cg = tid & 31;
    const int rb = tid >> 5;                 // 0..7
    const int xo = tx0 + 8 * cg;
    const int sb = 2 * cg;
    const int lr0 = 4 * rb;
    const int yb = 4 * rb;

    float4 vv[9];
    float4 ee;

    // prologue
    ISSUE_TILE(ty0, vv, ee);
    PACK_TILE(0, vv, ee);
    __syncthreads();

    // t=0: prefetch t1, compute t0
    ISSUE_TILE(ty0 + 1 * TH, vv, ee);
    __builtin_amdgcn_sched_barrier(0);       // pin loads above compute
    COMPUTE_TILE(0, ty0 + 0 * TH);
    PACK_TILE(1, vv, ee);
    __syncthreads();

    // t=1: prefetch t2, compute t1
    ISSUE_TILE(ty0 + 2 * TH, vv, ee);
    __builtin_amdgcn_sched_barrier(0);
    COMPUTE_TILE(1, ty0 + 1 * TH);
    PACK_TILE(0, vv, ee);
    __syncthreads();

    // t=2: prefetch t3, compute t2
    ISSUE_TILE(ty0 + 3 * TH, vv, ee);
    __builtin_amdgcn_sched_barrier(0);
    COMPUTE_TILE(0, ty0 + 2 * TH);
    PACK_TILE(1, vv, ee);
    __syncthreads();

    // t=3: compute (no prefetch)
    COMPUTE_TILE(1, ty0 + 3 * TH);
}

extern "C" void kernel_launch(void* const* d_in, const int* in_sizes, int n_in,
                              void* d_out, int out_size, void* d_ws, size_t ws_size,
                              hipStream_t stream) {
    const float* x = (const float*)d_in[0];
    float* out = (float*)d_out;
    dim3 grid(IMG_W / TW, IMG_H / (4 * TH), 96);  // 2 x 4 x 96 = 768 blocks = 3/CU exact
    dim3 block(256);
    lap_fused<<<grid, block, 0, stream>>>(x, out);
}